// Round 2
// baseline (1208.551 us; speedup 1.0000x reference)
//
#include <hip/hip_runtime.h>

typedef unsigned short u16;
typedef __bf16 bf16x8 __attribute__((ext_vector_type(8)));
typedef float f32x4 __attribute__((ext_vector_type(4)));
typedef short short8 __attribute__((ext_vector_type(8)));

#define TT 16
#define SP 1560           // th*tw = 30*52
#define CDIM 768
#define NHEADS 24
#define KP1 896           // padded K for MLP gemms (792 -> 896 = 14*64)
#define HSTR 896          // h storage stride (cols 792..895 zeros)
#define N1PAD 1024        // w1t padded N (792 -> 1024 = 4*256)

__device__ __forceinline__ float b2f(u16 u){
  unsigned int x = ((unsigned int)u) << 16;
  return __builtin_bit_cast(float, x);
}
__device__ __forceinline__ u16 f2b(float f){
  unsigned int x = __builtin_bit_cast(unsigned int, f);
  x += 0x7fffu + ((x >> 16) & 1u);
  return (u16)(x >> 16);
}
__device__ __forceinline__ float ldf(const void* p, size_t i, int f32){
  return f32 ? ((const float*)p)[i] : b2f(((const u16*)p)[i]);
}
__device__ __forceinline__ void g2l16(const void* g, void* l){
  __builtin_amdgcn_global_load_lds((const __attribute__((address_space(1))) void*)g,
                                   (__attribute__((address_space(3))) void*)l, 16, 0, 0);
}

// Decide input dtype: bf16 (flag=0) vs f32 (flag=1).
__global__ void detect_dtype(const u16* __restrict__ x, int* __restrict__ flag){
  __shared__ int sh[256];
  int tid = threadIdx.x;
  int cnt = 0;
  #pragma unroll
  for (int j=0;j<8;j++){
    u16 u = x[(size_t)(tid*8+j)*2];
    int e = (u >> 7) & 0xff;
    cnt += (e >= 90 && e <= 160) ? 1 : 0;
  }
  sh[tid] = cnt;
  __syncthreads();
  if (tid == 0){
    int s = 0;
    for (int k=0;k<256;k++) s += sh[k];
    *flag = (s < 1024) ? 1 : 0;
  }
}

__global__ void convert(const void* __restrict__ src, u16* __restrict__ dst,
                        int n, const int* __restrict__ flagp){
  int f = *flagp;
  int i = blockIdx.x*256 + threadIdx.x;
  int stride = gridDim.x*256;
  if (f){
    const float* s = (const float*)src;
    for (int j=i; j<n; j+=stride) dst[j] = f2b(s[j]);
  } else {
    const u16* s = (const u16*)src;
    for (int j=i; j<n; j+=stride) dst[j] = s[j];
  }
}

// gm table: [b*16][128] bf16; cols 0..23 = gathered mouse window, 24..127 = 0
__global__ void build_gm(const void* __restrict__ mouse, u16* __restrict__ gm,
                         int b, const int* __restrict__ flagp){
  int f = *flagp;
  int i = blockIdx.x*256 + threadIdx.x;
  if (i >= b*TT*128) return;
  int col = i & 127, tix = i >> 7;
  int t = tix & 15, bidx = tix >> 4;
  float v = 0.f;
  if (col < 24){
    int j = col >> 1, c = col & 1;
    int p = 4*t + j;
    if (p >= 12) v = ldf(mouse, (size_t)(bidx*61 + (p-12))*2 + c, f);
  }
  gm[i] = f2b(v);
}

// dst[n][k] = (k<K && n<N) ? src[k][n] : 0 ;  dst is Npad x Kpad (bf16)
__global__ void transpose_pad(const void* __restrict__ src, u16* __restrict__ dst,
                              int K, int N, int Kpad, int Npad,
                              const int* __restrict__ flagp){
  int f = *flagp;
  __shared__ u16 tile[32][33];
  int k0 = blockIdx.x*32, n0 = blockIdx.y*32;
  int tx = threadIdx.x, ty = threadIdx.y;   // 32 x 8
  #pragma unroll
  for (int i=0;i<32;i+=8){
    int k = k0+ty+i, n = n0+tx;
    u16 v = 0;
    if (k<K && n<N) v = f ? f2b(((const float*)src)[(size_t)k*N+n])
                          : ((const u16*)src)[(size_t)k*N+n];
    tile[ty+i][tx] = v;
  }
  __syncthreads();
  #pragma unroll
  for (int i=0;i<32;i+=8){
    int n = n0+ty+i, k = k0+tx;
    if (n<Npad && k<Kpad) dst[(size_t)n*Kpad+k] = tile[tx][ty+i];
  }
}

// ===========================================================================
// 256x256 tile, BK=64, 8 waves (2M x 4N), 8-phase counted-vmcnt schedule
// (guide §5 template, T1+T2+T3+T4+T5). LDS 128 KiB: A[2][256][64], B[2][256][64].
// Per phase: {ds_read A-quadrant (4xb128; +8 B at K-tile start) ; stage 1
// half-tile (2x global_load_lds_dwordx4, source pre-swizzled) ; s_barrier ;
// lgkmcnt(0) ; setprio(1) 16xMFMA setprio(0) ; [vmcnt(4) at ph3/ph7] ; s_barrier}.
// Stage schedule (iter i computes tiles 2i(buf0), 2i+1(buf1)):
//   ph0: A(2i+1)h0->buf1  ph1: A(2i+1)h1  ph2: B(2i+2)h0->buf0  ph3: B(2i+2)h1
//   ph4: A(2i+2)h0->buf0  ph5: A(2i+2)h1  ph6: B(2i+3)h0->buf1  ph7: B(2i+3)h1
// Every staged region's last reader finished >=1 barrier earlier (checked).
// vmcnt(4): at ph3-end the newest load needed for ph4-7 is A(2i+1)h1 (staged
// ph1); ph2+ph3 issued 4 younger loads. Same count at ph7-end.
// LDS swizzle (T2): byte offset o (row-major [256][64] bf16, 128 B rows) is
// stored/read at o ^ ((row&7)<<4); write side achieved by XORing the source
// 16B-chunk index (global_load_lds dest stays linear — rule #21).
// AMODE 1: A = xb for k<768, gm table (128-wide) for k>=768.
// EPI 0: store. 1: +bias(n<792), gelu. 2: +bias. 3: +X residual, flag-dtype.
// EPI 4: fused-qkv split store (n/768 selects C/Ck/Cv), ldc=768.
// ===========================================================================
template<int AMODE, int EPI>
__global__ __launch_bounds__(512, 2) void gemm256(
    const u16* __restrict__ A, int lda,
    const u16* __restrict__ Bt, int ldb, int Kpad,
    const u16* __restrict__ bias,
    const u16* __restrict__ X,
    const u16* __restrict__ gmtab,
    u16* __restrict__ C, u16* __restrict__ Ck, u16* __restrict__ Cv,
    int ldc, int nmax,
    const int* __restrict__ flagp)
{
  __shared__ __attribute__((aligned(16))) u16 sA[2][256*64];
  __shared__ __attribute__((aligned(16))) u16 sB[2][256*64];

  // ---- bijective XCD swizzle (m204 formula) ----
  const int gx = gridDim.x;
  const int nwg = gx * gridDim.y;
  const int orig = blockIdx.y * gx + blockIdx.x;
  const int q8 = nwg >> 3, r8 = nwg & 7;
  const int xcd = orig & 7, idx = orig >> 3;
  const int nl = (xcd < r8 ? xcd*(q8+1) : r8*(q8+1) + (xcd-r8)*q8) + idx;
  const int bx = nl % gx, by = nl / gx;

  const int tid = threadIdx.x;
  const int wave = tid >> 6, lane = tid & 63;
  const int wm8 = wave >> 2, wn8 = wave & 3;     // 2 x 4 wave grid
  const int lrow = lane & 15, hi16 = lane >> 4;
  const int m0 = by*256, n0 = bx*256;

  f32x4 acc[8][4];
  #pragma unroll
  for (int r=0;r<8;r++)
    #pragma unroll
    for (int c=0;c<4;c++) acc[r][c] = (f32x4){0.f,0.f,0.f,0.f};

  const int nt = Kpad >> 6;        // K-tiles (even: 12 or 14)
  const int niter = nt >> 1;

  // stage one 128-row half-tile (16 KB = 2 issues of 512x16B)
  auto STAGE = [&](int isB, int buf, int half, int k0){
    #pragma unroll
    for (int is=0; is<2; is++){
      int r = half*128 + is*64 + (tid>>3);          // row within 256-row tile
      int ck = (((tid&7) ^ (r&7)) << 3);            // pre-swizzled source chunk
      const u16* src;
      if (isB){
        src = Bt + (size_t)(n0 + r)*ldb + k0 + ck;
      } else {
        int m = m0 + r;
        if (AMODE==1 && k0 >= CDIM) src = gmtab + (size_t)(m/SP)*128 + (k0 - CDIM) + ck;
        else                        src = A + (size_t)m*lda + k0 + ck;
      }
      char* l = (char*)(isB ? &sB[buf][0] : &sA[buf][0]) + half*16384 + is*8192 + wave*1024;
      g2l16(src, l);
    }
  };

  bf16x8 bfr[8];                  // B frags for current K-tile (4 nf x 2 ksub)
  auto LDB_ALL = [&](int buf){
    #pragma unroll
    for (int nn=0; nn<4; nn++){
      int r = wn8*64 + nn*16 + lrow;
      #pragma unroll
      for (int ks=0; ks<2; ks++){
        int o = (r<<7) + (ks<<6) + (hi16<<4);
        o ^= (r&7)<<4;
        bfr[nn*2+ks] = *(const bf16x8*)((const char*)&sB[buf][0] + o);
      }
    }
  };

  auto PHASE = [&](int q, int buf, int sIsB, int sbuf, int shalf, int sk0, int vm_end){
    bf16x8 a[4];
    #pragma unroll
    for (int mm=0; mm<2; mm++){
      int r = wm8*128 + (q*2+mm)*16 + lrow;
      #pragma unroll
      for (int ks=0; ks<2; ks++){
        int o = (r<<7) + (ks<<6) + (hi16<<4);
        o ^= (r&7)<<4;
        a[mm*2+ks] = *(const bf16x8*)((const char*)&sA[buf][0] + o);
      }
    }
    if (q==0) LDB_ALL(buf);
    STAGE(sIsB, sbuf, shalf, sk0);
    __builtin_amdgcn_s_barrier();
    asm volatile("s_waitcnt lgkmcnt(0)" ::: "memory");
    __builtin_amdgcn_sched_barrier(0);
    __builtin_amdgcn_s_setprio(1);
    #pragma unroll
    for (int mm=0; mm<2; mm++)
      #pragma unroll
      for (int nf=0; nf<4; nf++)
        #pragma unroll
        for (int ks=0; ks<2; ks++)
          acc[q*2+mm][nf] = __builtin_amdgcn_mfma_f32_16x16x32_bf16(
              a[mm*2+ks], bfr[nf*2+ks], acc[q*2+mm][nf], 0, 0, 0);
    __builtin_amdgcn_s_setprio(0);
    if (vm_end) asm volatile("s_waitcnt vmcnt(4)" ::: "memory");
    __builtin_amdgcn_s_barrier();
  };

  // ---- prologue: B(0), A(0), B(1) = 6 half-tiles (12 loads) ----
  STAGE(1,0,0,0); STAGE(1,0,1,0);
  STAGE(0,0,0,0); STAGE(0,0,1,0);
  STAGE(1,1,0,64); STAGE(1,1,1,64);
  asm volatile("s_waitcnt vmcnt(4)" ::: "memory");   // B(0),A(0) landed
  __builtin_amdgcn_s_barrier();

  for (int i=0; i<niter; ++i){
    int kA1 = (2*i+1) << 6;
    int t2 = 2*i+2; if (t2 > nt-1) t2 = nt-1;
    int t3 = 2*i+3; if (t3 > nt-1) t3 = nt-1;
    int k2 = t2 << 6, k3 = t3 << 6;
    PHASE(0, 0, 0, 1, 0, kA1, 0);
    PHASE(1, 0, 0, 1, 1, kA1, 0);
    PHASE(2, 0, 1, 0, 0, k2,  0);
    PHASE(3, 0, 1, 0, 1, k2,  1);
    PHASE(0, 1, 0, 0, 0, k2,  0);
    PHASE(1, 1, 0, 0, 1, k2,  0);
    PHASE(2, 1, 1, 1, 0, k3,  0);
    PHASE(3, 1, 1, 1, 1, k3,  1);
  }
  asm volatile("s_waitcnt vmcnt(0)" ::: "memory");   // drain tail stages

  // ---- epilogue (C/D layout: col = lane&15, row = hi16*4 + i) ----
  int f32out = 0;
  if constexpr (EPI==3) f32out = *flagp;
  #pragma unroll
  for (int nf=0; nf<4; nf++){
    int n = n0 + wn8*64 + nf*16 + lrow;
    float bv = 0.f;
    if (EPI==1) bv = (n < 792) ? b2f(bias[n]) : 0.f;
    if (EPI==2) bv = b2f(bias[n]);
    u16* dstb = C;
    int nn = n;
    if constexpr (EPI==4){
      int sec = n / 768;
      nn = n - sec*768;
      dstb = (sec==0) ? C : ((sec==1) ? Ck : Cv);
    }
    #pragma unroll
    for (int mf=0; mf<8; mf++){
      #pragma unroll
      for (int i2=0; i2<4; i2++){
        int m = m0 + wm8*128 + mf*16 + hi16*4 + i2;
        float v = acc[mf][nf][i2] + bv;
        if (EPI==1){
          float u = 0.7978845608028654f*(v + 0.044715f*v*v*v);
          v = 0.5f*v*(1.f + tanhf(u));
        }
        if (EPI==3) v += b2f(X[(size_t)m*CDIM + n]);
        if (n < nmax){
          if constexpr (EPI==3){
            if (f32out) ((float*)C)[(size_t)m*ldc + n] = v;
            else        C[(size_t)m*ldc + n] = f2b(v);
          } else {
            dstb[(size_t)m*ldc + nn] = f2b(v);
          }
        }
      }
    }
  }
}

// one wave per (batch, spatial, head): rmsnorm + rope on q/k, 16x16 softmax, PV
__global__ __launch_bounds__(256) void attn_kernel(
    const u16* __restrict__ qp, const u16* __restrict__ kp,
    const u16* __restrict__ vp, const u16* __restrict__ qg,
    const u16* __restrict__ kg, u16* __restrict__ outp)
{
  __shared__ float qs[4][16][32];
  __shared__ float ks[4][16][32];
  __shared__ float vs[4][16][32];
  __shared__ float ps[4][16][16];
  const int tid = threadIdx.x;
  const int wave = tid >> 6, lane = tid & 63;
  const int inst = blockIdx.x*4 + wave;
  const int head = inst % NHEADS;
  const int bs   = inst / NHEADS;
  const int s = bs % SP, bidx = bs / SP;
  const int t = lane >> 2, ch = lane & 3;
  const size_t mrow = (size_t)(bidx*TT + t)*SP + s;
  const size_t off = mrow*CDIM + head*32 + ch*8;

  float qf[8], kf[8], vf[8];
  {
    short8 r0 = *(const short8*)(qp + off);
    short8 r1 = *(const short8*)(kp + off);
    short8 r2 = *(const short8*)(vp + off);
    #pragma unroll
    for (int j=0;j<8;j++){ qf[j]=b2f((u16)r0[j]); kf[j]=b2f((u16)r1[j]); vf[j]=b2f((u16)r2[j]); }
  }
  float ssq=0.f, ssk=0.f;
  #pragma unroll
  for (int j=0;j<8;j++){ ssq += qf[j]*qf[j]; ssk += kf[j]*kf[j]; }
  ssq += __shfl_xor(ssq,1); ssq += __shfl_xor(ssq,2);
  ssk += __shfl_xor(ssk,1); ssk += __shfl_xor(ssk,2);
  float rq = rsqrtf(ssq*(1.f/32.f) + 1e-6f);
  float rk = rsqrtf(ssk*(1.f/32.f) + 1e-6f);
  #pragma unroll
  for (int j=0;j<8;j++){
    int d = ch*8 + j;
    qf[j] *= rq * b2f(qg[d]);
    kf[j] *= rk * b2f(kg[d]);
  }
  #pragma unroll
  for (int u=0;u<4;u++){
    int p = ch*4 + u;
    if (p < 12){
      float ang = (float)t * exp2f(-0.66666667f * (float)p);
      float sn, cs;
      __sincosf(ang, &sn, &cs);
      float a=qf[2*u], b=qf[2*u+1];
      qf[2*u]   = a*cs - b*sn;
      qf[2*u+1] = b*cs + a*sn;
      a=kf[2*u]; b=kf[2*u+1];
      kf[2*u]   = a*cs - b*sn;
      kf[2*u+1] = b*cs + a*sn;
    }
  }
  #pragma unroll
  for (int j=0;j<8;j++){
    qs[wave][t][ch*8+j]=qf[j];
    ks[wave][t][ch*8+j]=kf[j];
    vs[wave][t][ch*8+j]=vf[j];
  }
  __syncthreads();
  float sc[4]; float mx = -3.4e38f;
  #pragma unroll
  for (int jj=0;jj<4;jj++){
    int j = ch*4 + jj;
    float d = 0.f;
    #pragma unroll
    for (int dd=0;dd<32;dd++) d += qs[wave][t][dd]*ks[wave][j][dd];
    sc[jj] = d * 0.17677669529663689f;
    mx = fmaxf(mx, sc[jj]);
  }
  mx = fmaxf(mx, __shfl_xor(mx,1)); mx = fmaxf(mx, __shfl_xor(mx,2));
  float sum=0.f; float ex[4];
  #pragma unroll
  for (int jj=0;jj<4;jj++){ ex[jj]=__expf(sc[jj]-mx); sum+=ex[jj]; }
  sum += __shfl_xor(sum,1); sum += __shfl_xor(sum,2);
  float inv = 1.f/sum;
  #pragma unroll
  for (int jj=0;jj<4;jj++) ps[wave][t][ch*4+jj] = ex[jj]*inv;
  __syncthreads();
  float o[8] = {0,0,0,0,0,0,0,0};
  #pragma unroll
  for (int j=0;j<16;j++){
    float p = ps[wave][t][j];
    #pragma unroll
    for (int dd=0;dd<8;dd++) o[dd] += p * vs[wave][j][ch*8+dd];
  }
  union { short8 v; u16 u[8]; } pk;
  #pragma unroll
  for (int dd=0;dd<8;dd++) pk.u[dd] = f2b(o[dd]);
  *(short8*)(outp + off) = pk.v;
}

extern "C" void kernel_launch(void* const* d_in, const int* in_sizes, int n_in,
                              void* d_out, int out_size, void* d_ws, size_t ws_size,
                              hipStream_t stream){
  const void* mouse = d_in[0];
  // d_in[1] keyboard_condition: unused by the reference
  const void* x     = d_in[2];
  const void* w1    = d_in[3];
  const void* b1    = d_in[4];
  const void* w2    = d_in[5];
  const void* b2    = d_in[6];
  const void* qkvw  = d_in[7];
  const void* qg    = d_in[8];
  const void* kg    = d_in[9];
  const void* projw = d_in[10];
  const int b = in_sizes[0] / (61*2);       // nf=61, mouse_dim=2
  const int M = b * TT * SP;                // 49920 rows, x row order (b,t,s)

  u16* ws    = (u16*)d_ws;
  int* flag  = (int*)ws;                         // 32 u16 reserved
  u16* gm    = ws + 32;                          // b*16*128
  u16* bcvt  = gm + (size_t)b*TT*128;            // 2048: b1b 800 | b2b 768 | qgb 32 | kgb 32
  u16* b1b   = bcvt;
  u16* b2b   = bcvt + 800;
  u16* qgb   = bcvt + 1568;
  u16* kgb   = bcvt + 1600;
  u16* w1t   = bcvt + 2048;                      // 1024 x 896
  u16* w2t   = w1t  + (size_t)N1PAD*KP1;         // 768 x 896
  u16* qkvt  = w2t  + (size_t)CDIM*KP1;          // 2304 x 768
  u16* projt = qkvt + (size_t)(3*CDIM)*CDIM;     // 768 x 768
  u16* xb    = projt+ (size_t)CDIM*CDIM;         // M x 768 (bf16 copy of x)
  u16* h     = xb   + (size_t)M*CDIM;            // M x 896
  u16* feat  = h    + (size_t)M*HSTR;            // M x 768
  u16* kbuf  = feat + (size_t)M*CDIM;            // M x 768
  u16* vbuf  = kbuf + (size_t)M*CDIM;            // M x 768
  u16* qbuf  = h;                                // alias (h dead after gemm2)
  u16* attn  = feat;                             // alias (feat dead after qkv gemm)

  detect_dtype<<<1, 256, 0, stream>>>((const u16*)x, flag);
  convert<<<dim3(4),    256, 0, stream>>>(b1, b1b, 792, flag);
  convert<<<dim3(3),    256, 0, stream>>>(b2, b2b, 768, flag);
  convert<<<dim3(1),    256, 0, stream>>>(qg, qgb, 32, flag);
  convert<<<dim3(1),    256, 0, stream>>>(kg, kgb, 32, flag);
  convert<<<dim3(8192), 256, 0, stream>>>(x,  xb,  M*CDIM, flag);
  build_gm<<<dim3((b*TT*128+255)/256), 256, 0, stream>>>(mouse, gm, b, flag);
  dim3 tb(32,8);
  transpose_pad<<<dim3(KP1/32,  N1PAD/32),    tb, 0, stream>>>(w1,   w1t,   792,  792,    KP1,  N1PAD, flag);
  transpose_pad<<<dim3(KP1/32,  CDIM/32),     tb, 0, stream>>>(w2,   w2t,   792,  CDIM,   KP1,  CDIM,  flag);
  transpose_pad<<<dim3(CDIM/32, (3*CDIM)/32), tb, 0, stream>>>(qkvw, qkvt,  CDIM, 3*CDIM, CDIM, 3*CDIM,flag);
  transpose_pad<<<dim3(CDIM/32, CDIM/32),     tb, 0, stream>>>(projw, projt, CDIM, CDIM,  CDIM, CDIM,  flag);

  // MLP
  gemm256<1,1><<<dim3(N1PAD/256, M/256), 512, 0, stream>>>(xb,  CDIM, w1t, KP1, KP1, b1b, nullptr, gm,
                                                           h,   nullptr, nullptr, HSTR, 896, flag);
  gemm256<0,2><<<dim3(CDIM/256,  M/256), 512, 0, stream>>>(h,   HSTR, w2t, KP1, KP1, b2b, nullptr, nullptr,
                                                           feat, nullptr, nullptr, CDIM, 768, flag);
  // fused QKV: one N=2304 gemm, split store into q (h alias) / kbuf / vbuf
  gemm256<0,4><<<dim3((3*CDIM)/256, M/256), 512, 0, stream>>>(feat, CDIM, qkvt, CDIM, CDIM, nullptr, nullptr, nullptr,
                                                              qbuf, kbuf, vbuf, CDIM, 3*CDIM, flag);
  attn_kernel<<<dim3(b*SP*NHEADS/4), 256, 0, stream>>>(qbuf, kbuf, vbuf, qgb, kgb, attn);
  gemm256<0,3><<<dim3(CDIM/256,  M/256), 512, 0, stream>>>(attn, CDIM, projt, CDIM, CDIM, nullptr, xb, nullptr,
                                                           (u16*)d_out, nullptr, nullptr, CDIM, 768, flag);
}

// Round 3
// 935.857 us; speedup vs baseline: 1.2914x; 1.2914x over previous
//
#include <hip/hip_runtime.h>

typedef unsigned short u16;
typedef __bf16 bf16x8 __attribute__((ext_vector_type(8)));
typedef float f32x4 __attribute__((ext_vector_type(4)));
typedef short short8 __attribute__((ext_vector_type(8)));

#define TT 16
#define SP 1560           // th*tw = 30*52
#define CDIM 768
#define NHEADS 24
#define KP 800            // padded K for MLP gemms (792 -> 800 = 25*32)
#define HROWS 896         // padded N for gemm1 B tile coverage (792 -> 896 = 7*128)
#define HSTR 800          // h storage stride (cols 792..799 = gelu(0)=0)

__device__ __forceinline__ float b2f(u16 u){
  unsigned int x = ((unsigned int)u) << 16;
  return __builtin_bit_cast(float, x);
}
__device__ __forceinline__ u16 f2b(float f){
  unsigned int x = __builtin_bit_cast(unsigned int, f);
  x += 0x7fffu + ((x >> 16) & 1u);
  return (u16)(x >> 16);
}
__device__ __forceinline__ float ldf(const void* p, size_t i, int f32){
  return f32 ? ((const float*)p)[i] : b2f(((const u16*)p)[i]);
}
__device__ __forceinline__ void g2l16(const void* g, void* l){
  __builtin_amdgcn_global_load_lds((const __attribute__((address_space(1))) void*)g,
                                   (__attribute__((address_space(3))) void*)l, 16, 0, 0);
}

// Decide input dtype: bf16 (flag=0) vs f32 (flag=1).
__global__ void detect_dtype(const u16* __restrict__ x, int* __restrict__ flag){
  __shared__ int sh[256];
  int tid = threadIdx.x;
  int cnt = 0;
  #pragma unroll
  for (int j=0;j<8;j++){
    u16 u = x[(size_t)(tid*8+j)*2];
    int e = (u >> 7) & 0xff;
    cnt += (e >= 90 && e <= 160) ? 1 : 0;
  }
  sh[tid] = cnt;
  __syncthreads();
  if (tid == 0){
    int s = 0;
    for (int k=0;k<256;k++) s += sh[k];
    *flag = (s < 1024) ? 1 : 0;
  }
}

__global__ void convert(const void* __restrict__ src, u16* __restrict__ dst,
                        int n, const int* __restrict__ flagp){
  int f = *flagp;
  int i = blockIdx.x*256 + threadIdx.x;
  int stride = gridDim.x*256;
  if (f){
    const float* s = (const float*)src;
    for (int j=i; j<n; j+=stride) dst[j] = f2b(s[j]);
  } else {
    const u16* s = (const u16*)src;
    for (int j=i; j<n; j+=stride) dst[j] = s[j];
  }
}

// gm table: [b*16][32] bf16; cols 0..23 = gathered mouse window, 24..31 = 0
__global__ void build_gm(const void* __restrict__ mouse, u16* __restrict__ gm,
                         int b, const int* __restrict__ flagp){
  int f = *flagp;
  int i = blockIdx.x*256 + threadIdx.x;
  if (i >= b*TT*32) return;
  int col = i & 31, tix = i >> 5;
  int t = tix & 15, bidx = tix >> 4;
  float v = 0.f;
  if (col < 24){
    int j = col >> 1, c = col & 1;
    int p = 4*t + j;
    if (p >= 12) v = ldf(mouse, (size_t)(bidx*61 + (p-12))*2 + c, f);
  }
  gm[i] = f2b(v);
}

// dst[n][k] = (k<K && n<N) ? src[k][n] : 0 ;  dst is Npad x Kpad (bf16)
__global__ void transpose_pad(const void* __restrict__ src, u16* __restrict__ dst,
                              int K, int N, int Kpad, int Npad,
                              const int* __restrict__ flagp){
  int f = *flagp;
  __shared__ u16 tile[32][33];
  int k0 = blockIdx.x*32, n0 = blockIdx.y*32;
  int tx = threadIdx.x, ty = threadIdx.y;   // 32 x 8
  #pragma unroll
  for (int i=0;i<32;i+=8){
    int k = k0+ty+i, n = n0+tx;
    u16 v = 0;
    if (k<K && n<N) v = f ? f2b(((const float*)src)[(size_t)k*N+n])
                          : ((const u16*)src)[(size_t)k*N+n];
    tile[ty+i][tx] = v;
  }
  __syncthreads();
  #pragma unroll
  for (int i=0;i<32;i+=8){
    int n = n0+ty+i, k = k0+tx;
    if (n<Npad && k<Kpad) dst[(size_t)n*Kpad+k] = tile[tx][ty+i];
  }
}

// ===========================================================================
// gemm128: 128x128 tile, BK=32, 4 waves, 2-phase dbuf (R1-proven structure),
// + LDS-staged coalesced epilogue (smem reused as the 32KB C tile).
// AMODE 1: A = xb for k<768, gm table for k>=768.
// EPI 1: +bias(n<792), gelu. 2: +bias. 3: +X residual, flag-dtype store.
// ===========================================================================
template<int AMODE, int EPI>
__global__ __launch_bounds__(256, 4) void gemm128(
    const u16* __restrict__ A, int lda,
    const u16* __restrict__ Bt, int ldb, int Kpad,
    const u16* __restrict__ bias,
    const u16* __restrict__ X,
    const u16* __restrict__ gmtab,
    u16* __restrict__ C, int ldc, int nmax,
    const int* __restrict__ flagp)
{
  __shared__ __attribute__((aligned(16))) u16 smem[16384];   // 32 KB
  // K-loop layout: A bytes [0,16384) (8192/buf), B bytes [16384,32768)
  int f32out = 0;
  if constexpr (EPI==3) f32out = *flagp;

  // ---- bijective XCD swizzle (m204) ----
  const int gx = gridDim.x;
  const int nwg = gx * gridDim.y;
  const int orig = blockIdx.y * gx + blockIdx.x;
  const int q8 = nwg >> 3, r8 = nwg & 7;
  const int xcd = orig & 7, idx = orig >> 3;
  const int nl = (xcd < r8 ? xcd*(q8+1) : r8*(q8+1) + (xcd-r8)*q8) + idx;
  const int bx = nl % gx, by = nl / gx;

  const int tid = threadIdx.x;
  const int wave = tid >> 6, lane = tid & 63;
  const int lrow = lane & 15, quad = lane >> 4;
  const int m0 = by * 128, n0 = bx * 128;
  const int wm = (wave >> 1) * 64, wn = (wave & 1) * 64;
  const int row = tid >> 2;          // 0..63
  const int kc  = (tid & 3) << 3;    // 0,8,16,24

  f32x4 acc[4][4];
  #pragma unroll
  for (int r=0;r<4;r++)
    #pragma unroll
    for (int c=0;c<4;c++) acc[r][c] = (f32x4){0.f,0.f,0.f,0.f};

  auto STAGE = [&](int bi, int k0){
    #pragma unroll
    for (int ch=0; ch<2; ch++){
      int m = m0 + ch*64 + row;
      const u16* srcA;
      if (AMODE==1 && k0 >= CDIM) srcA = gmtab + (m/SP)*32 + (k0 - CDIM) + kc;
      else                        srcA = A + (size_t)m*lda + k0 + kc;
      g2l16(srcA, (char*)smem + bi*8192 + ch*4096 + wave*1024);
      int n = n0 + ch*64 + row;
      const u16* srcB = Bt + (size_t)n*ldb + k0 + kc;
      g2l16(srcB, (char*)smem + 16384 + bi*8192 + ch*4096 + wave*1024);
    }
  };

  auto COMPUTE = [&](int bi){
    bf16x8 af[4], bfr[4];
    #pragma unroll
    for (int r=0;r<4;r++)
      af[r]  = *(const bf16x8*)((const char*)smem + bi*8192 + (wm + r*16 + lrow)*64 + quad*16);
    #pragma unroll
    for (int c=0;c<4;c++)
      bfr[c] = *(const bf16x8*)((const char*)smem + 16384 + bi*8192 + (wn + c*16 + lrow)*64 + quad*16);
    #pragma unroll
    for (int r=0;r<4;r++)
      #pragma unroll
      for (int c=0;c<4;c++)
        acc[r][c] = __builtin_amdgcn_mfma_f32_16x16x32_bf16(af[r], bfr[c], acc[r][c], 0, 0, 0);
  };

  const int nt = Kpad >> 5;
  STAGE(0, 0);
  __syncthreads();
  int cur = 0;
  for (int t = 0; t < nt-1; ++t){
    STAGE(cur^1, (t+1) << 5);
    COMPUTE(cur);
    __syncthreads();
    cur ^= 1;
  }
  COMPUTE(cur);
  __syncthreads();                // all waves done reading smem; DMAs drained

  // ---- epilogue (C/D layout: col = lane&15, row = quad*4 + i) ----
  if constexpr (EPI==3){
    if (f32out){
      #pragma unroll
      for (int c=0;c<4;c++){
        int n = n0 + wn + c*16 + lrow;
        #pragma unroll
        for (int r=0;r<4;r++){
          #pragma unroll
          for (int i=0;i<4;i++){
            int m = m0 + wm + r*16 + quad*4 + i;
            float v = acc[r][c][i] + b2f(X[(size_t)m*CDIM + n]);
            if (n < nmax) ((float*)C)[(size_t)m*ldc + n] = v;
          }
        }
      }
      return;
    }
  }
  // stage acc -> smem as bf16 [128][128]
  #pragma unroll
  for (int c=0;c<4;c++){
    int n = n0 + wn + c*16 + lrow;
    float bv = 0.f;
    if (EPI==1) bv = (n < 792) ? b2f(bias[n]) : 0.f;
    if (EPI==2) bv = b2f(bias[n]);
    #pragma unroll
    for (int r=0;r<4;r++){
      #pragma unroll
      for (int i=0;i<4;i++){
        int rw = wm + r*16 + quad*4 + i;
        float v = acc[r][c][i] + bv;
        if (EPI==1){
          float u = 0.7978845608028654f*(v + 0.044715f*v*v*v);
          v = 0.5f*v*(1.f + tanhf(u));
        }
        if (EPI==3) v += b2f(X[(size_t)(m0+rw)*CDIM + n]);
        smem[rw*128 + (wn + c*16 + lrow)] = f2b(v);
      }
    }
  }
  __syncthreads();
  // readback: 256 threads x 8 chunks of 16B, fully coalesced stores
  {
    int colu = (tid & 15) * 8;
    int n = n0 + colu;
    if (n < nmax){
      #pragma unroll
      for (int j=0;j<8;j++){
        int rw = (tid >> 4) + j*16;
        short8 vv = *(const short8*)&smem[rw*128 + colu];
        *(short8*)&C[(size_t)(m0+rw)*ldc + n] = vv;
      }
    }
  }
}

// ===========================================================================
// gemm256: 256x256 tile, BK=64, 8 waves, 8-phase counted-vmcnt schedule
// (T1+T2+T3+T4+T5), + LDS-staged coalesced epilogue (smem = 128KB C tile).
// EPI 4: fused-qkv split store (section from n0/768), ldc=768.
// ===========================================================================
template<int AMODE, int EPI>
__global__ __launch_bounds__(512, 2) void gemm256(
    const u16* __restrict__ A, int lda,
    const u16* __restrict__ Bt, int ldb, int Kpad,
    const u16* __restrict__ bias,
    const u16* __restrict__ X,
    const u16* __restrict__ gmtab,
    u16* __restrict__ C, u16* __restrict__ Ck, u16* __restrict__ Cv,
    int ldc, int nmax,
    const int* __restrict__ flagp)
{
  __shared__ __attribute__((aligned(16))) u16 smem[65536];   // 128 KB
  // K-loop layout: A bytes [0,65536) (32768/buf), B bytes [65536,131072)

  // ---- bijective XCD swizzle (m204) ----
  const int gx = gridDim.x;
  const int nwg = gx * gridDim.y;
  const int orig = blockIdx.y * gx + blockIdx.x;
  const int q8 = nwg >> 3, r8 = nwg & 7;
  const int xcd = orig & 7, idx = orig >> 3;
  const int nl = (xcd < r8 ? xcd*(q8+1) : r8*(q8+1) + (xcd-r8)*q8) + idx;
  const int bx = nl % gx, by = nl / gx;

  const int tid = threadIdx.x;
  const int wave = tid >> 6, lane = tid & 63;
  const int wm8 = wave >> 2, wn8 = wave & 3;     // 2 x 4 wave grid
  const int lrow = lane & 15, hi16 = lane >> 4;
  const int m0 = by*256, n0 = bx*256;

  f32x4 acc[8][4];
  #pragma unroll
  for (int r=0;r<8;r++)
    #pragma unroll
    for (int c=0;c<4;c++) acc[r][c] = (f32x4){0.f,0.f,0.f,0.f};

  const int nt = Kpad >> 6;        // even (12)
  const int niter = nt >> 1;

  auto STAGE = [&](int isB, int buf, int half, int k0){
    #pragma unroll
    for (int is=0; is<2; is++){
      int r = half*128 + is*64 + (tid>>3);
      int ck = (((tid&7) ^ (r&7)) << 3);            // pre-swizzled source chunk
      const u16* src;
      if (isB){
        src = Bt + (size_t)(n0 + r)*ldb + k0 + ck;
      } else {
        int m = m0 + r;
        if (AMODE==1 && k0 >= CDIM) src = gmtab + (size_t)(m/SP)*32 + (k0 - CDIM) + ck;
        else                        src = A + (size_t)m*lda + k0 + ck;
      }
      char* l = (char*)smem + (isB?65536:0) + buf*32768 + half*16384 + is*8192 + wave*1024;
      g2l16(src, l);
    }
  };

  bf16x8 bfr[8];
  auto LDB_ALL = [&](int buf){
    #pragma unroll
    for (int nn=0; nn<4; nn++){
      int r = wn8*64 + nn*16 + lrow;
      #pragma unroll
      for (int ks=0; ks<2; ks++){
        int o = (r<<7) + (ks<<6) + (hi16<<4);
        o ^= (r&7)<<4;
        bfr[nn*2+ks] = *(const bf16x8*)((const char*)smem + 65536 + buf*32768 + o);
      }
    }
  };

  auto PHASE = [&](int q, int buf, int sIsB, int sbuf, int shalf, int sk0, int vm_end){
    bf16x8 a[4];
    #pragma unroll
    for (int mm=0; mm<2; mm++){
      int r = wm8*128 + (q*2+mm)*16 + lrow;
      #pragma unroll
      for (int ks=0; ks<2; ks++){
        int o = (r<<7) + (ks<<6) + (hi16<<4);
        o ^= (r&7)<<4;
        a[mm*2+ks] = *(const bf16x8*)((const char*)smem + buf*32768 + o);
      }
    }
    if (q==0) LDB_ALL(buf);
    STAGE(sIsB, sbuf, shalf, sk0);
    __builtin_amdgcn_s_barrier();
    asm volatile("s_waitcnt lgkmcnt(0)" ::: "memory");
    __builtin_amdgcn_sched_barrier(0);
    __builtin_amdgcn_s_setprio(1);
    #pragma unroll
    for (int mm=0; mm<2; mm++)
      #pragma unroll
      for (int nf=0; nf<4; nf++)
        #pragma unroll
        for (int ks=0; ks<2; ks++)
          acc[q*2+mm][nf] = __builtin_amdgcn_mfma_f32_16x16x32_bf16(
              a[mm*2+ks], bfr[nf*2+ks], acc[q*2+mm][nf], 0, 0, 0);
    __builtin_amdgcn_s_setprio(0);
    if (vm_end) asm volatile("s_waitcnt vmcnt(4)" ::: "memory");
    __builtin_amdgcn_s_barrier();
  };

  // prologue: B(0), A(0), B(1)
  STAGE(1,0,0,0); STAGE(1,0,1,0);
  STAGE(0,0,0,0); STAGE(0,0,1,0);
  STAGE(1,1,0,64); STAGE(1,1,1,64);
  asm volatile("s_waitcnt vmcnt(4)" ::: "memory");
  __builtin_amdgcn_s_barrier();

  for (int i=0; i<niter; ++i){
    int kA1 = (2*i+1) << 6;
    int t2 = 2*i+2; if (t2 > nt-1) t2 = nt-1;
    int t3 = 2*i+3; if (t3 > nt-1) t3 = nt-1;
    int k2 = t2 << 6, k3 = t3 << 6;
    PHASE(0, 0, 0, 1, 0, kA1, 0);
    PHASE(1, 0, 0, 1, 1, kA1, 0);
    PHASE(2, 0, 1, 0, 0, k2,  0);
    PHASE(3, 0, 1, 0, 1, k2,  1);
    PHASE(0, 1, 0, 0, 0, k2,  0);
    PHASE(1, 1, 0, 0, 1, k2,  0);
    PHASE(2, 1, 1, 1, 0, k3,  0);
    PHASE(3, 1, 1, 1, 1, k3,  1);
  }
  asm volatile("s_waitcnt vmcnt(0)" ::: "memory");
  __syncthreads();                 // all DMAs drained in every wave

  // ---- staged epilogue ----
  int f32out = 0;
  if constexpr (EPI==3) f32out = *flagp;
  if constexpr (EPI==3){
    if (f32out){
      #pragma unroll
      for (int nf=0; nf<4; nf++){
        int n = n0 + wn8*64 + nf*16 + lrow;
        #pragma unroll
        for (int mf=0; mf<8; mf++){
          #pragma unroll
          for (int i2=0; i2<4; i2++){
            int m = m0 + wm8*128 + mf*16 + hi16*4 + i2;
            float v = acc[mf][nf][i2] + b2f(X[(size_t)m*CDIM + n]);
            if (n < nmax) ((float*)C)[(size_t)m*ldc + n] = v;
          }
        }
      }
      return;
    }
  }
  // stage acc -> smem as bf16 [256][256]
  #pragma unroll
  for (int nf=0; nf<4; nf++){
    int n = n0 + wn8*64 + nf*16 + lrow;
    float bv = 0.f;
    if (EPI==1) bv = (n < 792) ? b2f(bias[n]) : 0.f;
    if (EPI==2) bv = b2f(bias[n]);
    #pragma unroll
    for (int mf=0; mf<8; mf++){
      #pragma unroll
      for (int i2=0; i2<4; i2++){
        int rw = wm8*128 + mf*16 + hi16*4 + i2;
        float v = acc[mf][nf][i2] + bv;
        if (EPI==1){
          float u = 0.7978845608028654f*(v + 0.044715f*v*v*v);
          v = 0.5f*v*(1.f + tanhf(u));
        }
        if (EPI==3) v += b2f(X[(size_t)(m0+rw)*CDIM + n]);
        smem[rw*256 + (wn8*64 + nf*16 + lrow)] = f2b(v);
      }
    }
  }
  __syncthreads();
  // readback: 512 threads x 16 chunks of 16B, fully coalesced stores
  {
    int colu = (tid & 31) * 8;
    int n = n0 + colu;
    u16* dstb = C;
    int nn = n;
    if constexpr (EPI==4){
      int sec = n0 / 768;            // 256-wide tile lies in one section
      nn = n - sec*768;
      dstb = (sec==0) ? C : ((sec==1) ? Ck : Cv);
    }
    if (n < nmax){
      #pragma unroll
      for (int j=0;j<16;j++){
        int rw = (tid >> 5) + j*16;
        short8 vv = *(const short8*)&smem[rw*256 + colu];
        *(short8*)&dstb[(size_t)(m0+rw)*ldc + nn] = vv;
      }
    }
  }
}

// one wave per (batch, spatial, head): rmsnorm + rope on q/k, 16x16 softmax, PV
__global__ __launch_bounds__(256) void attn_kernel(
    const u16* __restrict__ qp, const u16* __restrict__ kp,
    const u16* __restrict__ vp, const u16* __restrict__ qg,
    const u16* __restrict__ kg, u16* __restrict__ outp)
{
  __shared__ float qs[4][16][32];
  __shared__ float ks[4][16][32];
  __shared__ float vs[4][16][32];
  __shared__ float ps[4][16][16];
  const int tid = threadIdx.x;
  const int wave = tid >> 6, lane = tid & 63;
  const int inst = blockIdx.x*4 + wave;
  const int head = inst % NHEADS;
  const int bs   = inst / NHEADS;
  const int s = bs % SP, bidx = bs / SP;
  const int t = lane >> 2, ch = lane & 3;
  const size_t mrow = (size_t)(bidx*TT + t)*SP + s;
  const size_t off = mrow*CDIM + head*32 + ch*8;

  float qf[8], kf[8], vf[8];
  {
    short8 r0 = *(const short8*)(qp + off);
    short8 r1 = *(const short8*)(kp + off);
    short8 r2 = *(const short8*)(vp + off);
    #pragma unroll
    for (int j=0;j<8;j++){ qf[j]=b2f((u16)r0[j]); kf[j]=b2f((u16)r1[j]); vf[j]=b2f((u16)r2[j]); }
  }
  float ssq=0.f, ssk=0.f;
  #pragma unroll
  for (int j=0;j<8;j++){ ssq += qf[j]*qf[j]; ssk += kf[j]*kf[j]; }
  ssq += __shfl_xor(ssq,1); ssq += __shfl_xor(ssq,2);
  ssk += __shfl_xor(ssk,1); ssk += __shfl_xor(ssk,2);
  float rq = rsqrtf(ssq*(1.f/32.f) + 1e-6f);
  float rk = rsqrtf(ssk*(1.f/32.f) + 1e-6f);
  #pragma unroll
  for (int j=0;j<8;j++){
    int d = ch*8 + j;
    qf[j] *= rq * b2f(qg[d]);
    kf[j] *= rk * b2f(kg[d]);
  }
  #pragma unroll
  for (int u=0;u<4;u++){
    int p = ch*4 + u;
    if (p < 12){
      float ang = (float)t * exp2f(-0.66666667f * (float)p);
      float sn, cs;
      __sincosf(ang, &sn, &cs);
      float a=qf[2*u], b=qf[2*u+1];
      qf[2*u]   = a*cs - b*sn;
      qf[2*u+1] = b*cs + a*sn;
      a=kf[2*u]; b=kf[2*u+1];
      kf[2*u]   = a*cs - b*sn;
      kf[2*u+1] = b*cs + a*sn;
    }
  }
  #pragma unroll
  for (int j=0;j<8;j++){
    qs[wave][t][ch*8+j]=qf[j];
    ks[wave][t][ch*8+j]=kf[j];
    vs[wave][t][ch*8+j]=vf[j];
  }
  __syncthreads();
  float sc[4]; float mx = -3.4e38f;
  #pragma unroll
  for (int jj=0;jj<4;jj++){
    int j = ch*4 + jj;
    float d = 0.f;
    #pragma unroll
    for (int dd=0;dd<32;dd++) d += qs[wave][t][dd]*ks[wave][j][dd];
    sc[jj] = d * 0.17677669529663689f;
    mx = fmaxf(mx, sc[jj]);
  }
  mx = fmaxf(mx, __shfl_xor(mx,1)); mx = fmaxf(mx, __shfl_xor(mx,2));
  float sum=0.f; float ex[4];
  #pragma unroll
  for (int jj=0;jj<4;jj++){ ex[jj]=__expf(sc[jj]-mx); sum+=ex[jj]; }
  sum += __shfl_xor(sum,1); sum += __shfl_xor(sum,2);
  float inv = 1.f/sum;
  #pragma unroll
  for (int jj=0;jj<4;jj++) ps[wave][t][ch*4+jj] = ex[jj]*inv;
  __syncthreads();
  float o[8] = {0,0,0,0,0,0,0,0};
  #pragma unroll
  for (int j=0;j<16;j++){
    float p = ps[wave][t][j];
    #pragma unroll
    for (int dd=0;dd<8;dd++) o[dd] += p * vs[wave][j][ch*8+dd];
  }
  union { short8 v; u16 u[8]; } pk;
  #pragma unroll
  for (int dd=0;dd<8;dd++) pk.u[dd] = f2b(o[dd]);
  *(short8*)(outp + off) = pk.v;
}

extern "C" void kernel_launch(void* const* d_in, const int* in_sizes, int n_in,
                              void* d_out, int out_size, void* d_ws, size_t ws_size,
                              hipStream_t stream){
  const void* mouse = d_in[0];
  // d_in[1] keyboard_condition: unused by the reference
  const void* x     = d_in[2];
  const void* w1    = d_in[3];
  const void* b1    = d_in[4];
  const void* w2    = d_in[5];
  const void* b2    = d_in[6];
  const void* qkvw  = d_in[7];
  const void* qg    = d_in[8];
  const void* kg    = d_in[9];
  const void* projw = d_in[10];
  const int b = in_sizes[0] / (61*2);       // nf=61, mouse_dim=2
  const int M = b * TT * SP;                // 49920 rows, x row order (b,t,s)

  u16* ws    = (u16*)d_ws;
  int* flag  = (int*)ws;                         // 32 u16 reserved
  u16* gm    = ws + 32;                          // b*16*32
  u16* bcvt  = gm + 1024;                        // 2048: b1b 800 | b2b 768 | qgb 32 | kgb 32
  u16* b1b   = bcvt;
  u16* b2b   = bcvt + 800;
  u16* qgb   = bcvt + 1568;
  u16* kgb   = bcvt + 1600;
  u16* w1t   = bcvt + 2048;                      // 896 x 800
  u16* w2t   = w1t  + (size_t)HROWS*KP;          // 768 x 800
  u16* qkvt  = w2t  + (size_t)CDIM*KP;           // 2304 x 768
  u16* projt = qkvt + (size_t)(3*CDIM)*CDIM;     // 768 x 768
  u16* xb    = projt+ (size_t)CDIM*CDIM;         // M x 768 (bf16 copy of x)
  u16* h     = xb   + (size_t)M*CDIM;            // M x 800
  u16* feat  = h    + (size_t)M*HSTR;            // M x 768
  u16* kbuf  = feat + (size_t)M*CDIM;            // M x 768
  u16* vbuf  = kbuf + (size_t)M*CDIM;            // M x 768
  u16* qbuf  = h;                                // alias (h dead after gemm2)
  u16* attn  = feat;                             // alias (feat dead after qkv gemm)

  detect_dtype<<<1, 256, 0, stream>>>((const u16*)x, flag);
  convert<<<dim3(4),    256, 0, stream>>>(b1, b1b, 792, flag);
  convert<<<dim3(3),    256, 0, stream>>>(b2, b2b, 768, flag);
  convert<<<dim3(1),    256, 0, stream>>>(qg, qgb, 32, flag);
  convert<<<dim3(1),    256, 0, stream>>>(kg, kgb, 32, flag);
  convert<<<dim3(8192), 256, 0, stream>>>(x,  xb,  M*CDIM, flag);
  build_gm<<<dim3((b*TT*32+255)/256), 256, 0, stream>>>(mouse, gm, b, flag);
  dim3 tb(32,8);
  transpose_pad<<<dim3(KP/32,   HROWS/32),    tb, 0, stream>>>(w1,   w1t,   792,  792,    KP,   HROWS, flag);
  transpose_pad<<<dim3(KP/32,   CDIM/32),     tb, 0, stream>>>(w2,   w2t,   792,  CDIM,   KP,   CDIM,  flag);
  transpose_pad<<<dim3(CDIM/32, (3*CDIM)/32), tb, 0, stream>>>(qkvw, qkvt,  CDIM, 3*CDIM, CDIM, 3*CDIM,flag);
  transpose_pad<<<dim3(CDIM/32, CDIM/32),     tb, 0, stream>>>(projw, projt, CDIM, CDIM,  CDIM, CDIM,  flag);

  // MLP (128^2 2-phase)
  gemm128<1,1><<<dim3(HROWS/128, M/128), 256, 0, stream>>>(xb, CDIM, w1t, KP, KP, b1b, nullptr, gm,
                                                           h, HSTR, 800, flag);
  gemm128<0,2><<<dim3(CDIM/128,  M/128), 256, 0, stream>>>(h, HSTR, w2t, KP, KP, b2b, nullptr, nullptr,
                                                           feat, CDIM, 768, flag);
  // fused QKV (256^2 8-phase): one N=2304 gemm, split store q/k/v
  gemm256<0,4><<<dim3((3*CDIM)/256, M/256), 512, 0, stream>>>(feat, CDIM, qkvt, CDIM, CDIM, nullptr, nullptr, nullptr,
                                                              qbuf, kbuf, vbuf, CDIM, 3*CDIM, flag);
  attn_kernel<<<dim3(b*SP*NHEADS/4), 256, 0, stream>>>(qbuf, kbuf, vbuf, qgb, kgb, attn);
  gemm128<0,3><<<dim3(CDIM/128,  M/128), 256, 0, stream>>>(attn, CDIM, projt, CDIM, CDIM, nullptr, xb, nullptr,
                                                           (u16*)d_out, CDIM, 768, flag);
}